// Round 12
// baseline (314.396 us; speedup 1.0000x reference)
//
#include <hip/hip_runtime.h>
#include <math.h>

// WheelMultiheadAttention on MI355X (gfx950) — v13: v12 (XCD-swizzled attn) with PLAIN
// weight stores (completes the NT/plain x swizzle/no-swizzle A/B matrix: v8=259 NT/no-swz,
// v10=371 plain/no-swz, v12=253.5 NT/swz).
// B=2 T=2048 C=1024 H=16 D=64. Outputs: out [2,2048,1024] f32, weights [2,16,2048,2048] f32.

typedef _Float16 f16;
typedef _Float16 f16x2 __attribute__((ext_vector_type(2)));
typedef _Float16 f16x4 __attribute__((ext_vector_type(4)));
typedef _Float16 f16x8 __attribute__((ext_vector_type(8)));
typedef float  f32x2  __attribute__((ext_vector_type(2)));
typedef float  f32x4  __attribute__((ext_vector_type(4)));

#define MFMAH(a, b, c)  __builtin_amdgcn_mfma_f32_16x16x32_f16((a), (b), (c), 0, 0, 0)

__device__ __forceinline__ void gload16(void* lds, const void* g) {
  __builtin_amdgcn_global_load_lds((__attribute__((address_space(1))) void*)(g),
                                   (__attribute__((address_space(3))) void*)(lds),
                                   16, 0, 0);
}

// ---------------- fused f32 -> f16 convert (query|key|value|q_w|k_w|v_w|o_w) ----------------
__global__ __launch_bounds__(256) void conv_f16(const float* __restrict__ q, const float* __restrict__ k,
                                                const float* __restrict__ v, const float* __restrict__ qw,
                                                const float* __restrict__ kw, const float* __restrict__ vw,
                                                const float* __restrict__ ow, f16* __restrict__ xf) {
  long long i = ((long long)blockIdx.x * 256 + threadIdx.x) * 4;
  const float* src;
  long long off;
  if (i < 4194304)       { src = q;  off = 0; }
  else if (i < 8388608)  { src = k;  off = 4194304; }
  else if (i < 12582912) { src = v;  off = 8388608; }
  else if (i < 13631488) { src = qw; off = 12582912; }
  else if (i < 14680064) { src = kw; off = 13631488; }
  else if (i < 15728640) { src = vw; off = 14680064; }
  else                   { src = ow; off = 15728640; }
  f32x4 val = *(const f32x4*)(src + (i - off));
  f16x4 h;
#pragma unroll
  for (int r = 0; r < 4; ++r) h[r] = (f16)val[r];
  *(f16x4*)(xf + i) = h;
}

// ---------------- shared GEMM helpers (128x128 tile, K-step 32, stride-1024 sources) ----
__device__ __forceinline__ void stage_tile(f16* lds, const f16* g, int row0, int kc, int tid) {
#pragma unroll
  for (int j = 0; j < 2; ++j) {
    int chunk = j * 256 + tid;
    int r = chunk >> 2, cpos = chunk & 3;
    int csrc = cpos ^ ((r >> 1) & 3);
    gload16((char*)lds + chunk * 16,
            (const char*)(g + (size_t)(row0 + r) * 1024 + kc) + csrc * 16);
  }
}

__device__ __forceinline__ f16x8 frag_ld(const f16* lds, int row, int g) {
  int pos = g ^ ((row >> 1) & 3);
  return *(const f16x8*)((const char*)lds + row * 64 + pos * 16);
}

// K-loop core: acc[fm][fn] += A[o0+..][:] . X[t0+..][:] over K=1024
__device__ __forceinline__ void gemm_core(const f16* A, const f16* X, int o0, int t0, int tid,
                                          f16* sA, f16* sB, f32x4 acc[4][4]) {
  int wid = tid >> 6, lane = tid & 63;
  int wm = wid >> 1, wn = wid & 1, g = lane >> 4, r15 = lane & 15;
  for (int kc = 0; kc < 1024; kc += 32) {
    __syncthreads();
    stage_tile(sA, A, o0, kc, tid);
    stage_tile(sB, X, t0, kc, tid);
    __syncthreads();
    f16x8 a[4], x[4];
#pragma unroll
    for (int f = 0; f < 4; ++f) {
      a[f] = frag_ld(sA, wm * 64 + f * 16 + r15, g);
      x[f] = frag_ld(sB, wn * 64 + f * 16 + r15, g);
    }
#pragma unroll
    for (int fm = 0; fm < 4; ++fm)
#pragma unroll
      for (int fn = 0; fn < 4; ++fn)
        acc[fm][fn] = MFMAH(a[fm], x[fn], acc[fm][fn]);
  }
}

// ---------------- fused Q/K/V projections (blockIdx.z = 0:Q, 1:K, 2:V) ----------------
__global__ __launch_bounds__(256) void gemm_qkv(const f16* __restrict__ xf,
                                                const float* __restrict__ q_b, const float* __restrict__ k_b,
                                                const float* __restrict__ v_b,
                                                f16* __restrict__ Qf, f16* __restrict__ Kf,
                                                f16* __restrict__ VT2) {
  __shared__ f16 sA[4096], sB[4096];
  int z = blockIdx.z;
  int tid = threadIdx.x;
  int wid = tid >> 6, lane = tid & 63;
  int wm = wid >> 1, wn = wid & 1, g = lane >> 4, r15 = lane & 15;
  f32x4 acc[4][4] = {};
  if (z == 2) {
    const f16* X = xf + 8388608;   // value
    const f16* W = xf + 14680064;  // v_w
    int o0 = blockIdx.x * 128, t0 = blockIdx.y * 128;
    gemm_core(X, W, t0, o0, tid, sA, sB, acc);
#pragma unroll
    for (int fm = 0; fm < 4; ++fm)
#pragma unroll
      for (int fn = 0; fn < 4; ++fn) {
        int tb = t0 + wm * 64 + fm * 16 + 4 * g;
        int o  = o0 + wn * 64 + fn * 16 + r15;
        int bb = tb >> 11, tl = tb & 2047, hh = o >> 6, dd = o & 63;
        int ch = tl >> 5, c = tl & 31;
        int slotbase = (c < 16) ? ((c >> 2) << 3) : ((((c - 16) >> 2) << 3) + 4);
        float bo = v_b[o];
        f16x4 v4;
#pragma unroll
        for (int r = 0; r < 4; ++r) v4[r] = (f16)(acc[fm][fn][r] + bo);
        *(f16x4*)(VT2 + ((((size_t)bb * 16 + hh) * 64 + ch) * 64 + dd) * 32 + slotbase) = v4;
      }
  } else {
    const f16* A = xf + (z ? 13631488 : 12582912);
    const f16* X = xf + (z ? 4194304 : 0);
    const float* bias = z ? k_b : q_b;
    f16* Yf = z ? Kf : Qf;
    float scale = z ? 1.0f : 0.125f;
    int o0 = blockIdx.x * 128, t0 = blockIdx.y * 128;
    gemm_core(A, X, o0, t0, tid, sA, sB, acc);
#pragma unroll
    for (int fm = 0; fm < 4; ++fm)
#pragma unroll
      for (int fn = 0; fn < 4; ++fn) {
        int ob = o0 + wm * 64 + fm * 16 + 4 * g;
        int t  = t0 + wn * 64 + fn * 16 + r15;
        int bb = t >> 11, tl = t & 2047, hh = ob >> 6, dd = ob & 63;
        size_t base = (((size_t)bb * 16 + hh) * 2048 + tl) * 64 + dd;
        f16x4 vh;
#pragma unroll
        for (int r = 0; r < 4; ++r)
          vh[r] = (f16)((acc[fm][fn][r] + bias[ob + r]) * scale);
        *(f16x4*)(Yf + base) = vh;
      }
  }
}

// ---------------- O projection: Out[t][o] = A[t][:].o_w[o][:] + b, f32 ----------------
__global__ __launch_bounds__(256) void gemm_o(const f16* __restrict__ xf, const f16* __restrict__ Abuf,
                                              const float* __restrict__ o_b, float* __restrict__ OutF) {
  __shared__ f16 sA[4096], sB[4096];
  const f16* A = xf + 15728640;  // o_w
  int tid = threadIdx.x;
  int o0 = blockIdx.x * 128, t0 = blockIdx.y * 128;
  int wid = tid >> 6, lane = tid & 63;
  int wm = wid >> 1, wn = wid & 1, g = lane >> 4, r15 = lane & 15;
  f32x4 acc[4][4] = {};
  gemm_core(A, Abuf, o0, t0, tid, sA, sB, acc);
#pragma unroll
  for (int fm = 0; fm < 4; ++fm)
#pragma unroll
    for (int fn = 0; fn < 4; ++fn) {
      int ob = o0 + wm * 64 + fm * 16 + 4 * g;
      int t  = t0 + wn * 64 + fn * 16 + r15;
      f32x4 v;
#pragma unroll
      for (int r = 0; r < 4; ++r) v[r] = acc[fm][fn][r] + o_b[ob + r];
      *(f32x4*)(OutF + (size_t)t * 1024 + ob) = v;
    }
}

// ---------------- fused attention (v13 = v12 with PLAIN weight stores) ----------------
__global__ __launch_bounds__(512, 6) void attn_kernel(
    const f16* __restrict__ Qf, const f16* __restrict__ Kf,
    const f16* __restrict__ VT2, const int* __restrict__ mask,
    float* __restrict__ wout, f16* __restrict__ Abuf) {
  __shared__ char smemA[8][4224];  // per-wave: phase1 K dbuf (2x2048B) -> phase2 pstage
  __shared__ f16 pvh[8][16][72];   // PV partials f16
  __shared__ float ps[128];        // row-sum partials [q][wave]
  __shared__ float rz[16];
  int tid = threadIdx.x;
  int wid = tid >> 6, lane = tid & 63;
  int g = lane >> 4, r15 = lane & 15;
  // XCD-aware bijective swizzle: each XCD gets a contiguous 512-block slice (4 bh).
  int bid = blockIdx.x;
  int swz = (bid & 7) * 512 + (bid >> 3);
  int qt = swz & 127, bh = swz >> 7;
  int b = bh >> 4, h = bh & 15;
  int q0 = qt * 16;

  // Q fragments (B-operand: col = q = lane&15). 1/8 scale folded into Qf.
  const f16* qp = Qf + ((size_t)bh * 2048 + q0 + r15) * 64 + 8 * g;
  f16x8 qh0 = *(const f16x8*)(qp);
  f16x8 qh1 = *(const f16x8*)(qp + 32);

  // pack this lane's 64 mask bits (k = wid*256 + s*16 + 4g + r) -> bit 4s+r
  const int* mp = mask + b * 2048 + wid * 256 + 4 * g;
  unsigned long long mb = 0;
#pragma unroll
  for (int t = 0; t < 16; ++t) {
    int4 ma = *(const int4*)(mp + t * 16);
    mb |= ((ma.x ? 1ull : 0ull) << (4 * t)) | ((ma.y ? 1ull : 0ull) << (4 * t + 1)) |
          ((ma.z ? 1ull : 0ull) << (4 * t + 2)) | ((ma.w ? 1ull : 0ull) << (4 * t + 3));
  }

  // ---- phase 1: swapped QK^T, async-LDS K staging, ds_reads pipelined 1 tile ahead ----
  f16* kb0 = (f16*)&smemA[wid][0];
  f16* kb1 = (f16*)&smemA[wid][2048];
  const f16* ksrcA = Kf + ((size_t)bh * 2048 + wid * 256 + (lane >> 3)) * 64 +
                     (((lane & 7) ^ ((lane >> 3) & 7)) * 8);
  const f16* ksrcB = ksrcA + 8 * 64;

  gload16(kb0, ksrcA);
  gload16(kb0 + 512, ksrcB);
  gload16(kb1, ksrcA + 1024);
  gload16(kb1 + 512, ksrcB + 1024);
  asm volatile("s_waitcnt vmcnt(2)" ::: "memory");  // tile 0 staged
  int key = r15 & 7;
  f16x8 c0 = *(const f16x8*)(kb0 + r15 * 64 + ((g ^ key) * 8));
  f16x8 c1 = *(const f16x8*)(kb0 + r15 * 64 + (((g + 4) ^ key) * 8));

  float psum = 0.f;
  f16x4 p16[16];
#pragma unroll
  for (int s = 0; s < 16; ++s) {
    if (s < 14) {
      asm volatile("s_waitcnt lgkmcnt(0)" ::: "memory");  // tile-s frag reads done
      f16* nb = (s & 1) ? kb1 : kb0;
      gload16(nb, ksrcA + (s + 2) * 1024);
      gload16(nb + 512, ksrcB + (s + 2) * 1024);
    }
    f16x8 n0, n1;
    if (s < 15) {
      if (s < 14) asm volatile("s_waitcnt vmcnt(2)" ::: "memory");
      else        asm volatile("s_waitcnt vmcnt(0)" ::: "memory");
      const f16* nt = ((s + 1) & 1) ? kb1 : kb0;
      n0 = *(const f16x8*)(nt + r15 * 64 + ((g ^ key) * 8));
      n1 = *(const f16x8*)(nt + r15 * 64 + (((g + 4) ^ key) * 8));
    }
    f32x4 sc = {0.f, 0.f, 0.f, 0.f};
    sc = MFMAH(c0, qh0, sc);   // A = K rows (k), B = Q (cols q)
    sc = MFMAH(c1, qh1, sc);
    f16x4 pk;
#pragma unroll
    for (int r = 0; r < 4; ++r) {
      float e = ((mb >> (4 * s + r)) & 1) ? 0.f : __expf(sc[r]);
      psum += e;
      pk[r] = (f16)e;
    }
    p16[s] = pk;
    c0 = n0;
    c1 = n1;
  }

  // in-wave row-sum reduce across g (lanes sharing q=r15)
  psum += __shfl_xor(psum, 16);
  psum += __shfl_xor(psum, 32);
  if (lane < 16) ps[lane * 8 + wid] = psum;
  __syncthreads();

  // finalize row sums -> rz (wheel: z==0 -> 0)
  if (tid < 128) {
    float z = ps[tid];
#pragma unroll
    for (int m = 1; m <= 4; m <<= 1) z += __shfl_xor(z, m);
    if ((tid & 7) == 0) rz[tid >> 3] = (z > 0.f) ? 1.0f / z : 0.0f;
  }
  __syncthreads();

  // ---- phase 2: PV + transpose-staged contiguous PLAIN weight stores ----
  f32x4 acc[4] = {};
  {
    char* pst = &smemA[wid][0];
    int c5 = lane & 31, hi5 = lane >> 5;
    float* wrowbase = wout + ((size_t)bh * 2048 + q0) * 2048 + wid * 256;
    const f16* vb = VT2 + (((size_t)bh * 64 + wid * 8) * 64 + r15) * 32 + g * 8;
    f16x8 v0 = *(const f16x8*)(vb);
    f16x8 v1 = *(const f16x8*)(vb + 512);
    f16x8 v2 = *(const f16x8*)(vb + 1024);
    f16x8 v3 = *(const f16x8*)(vb + 1536);
#pragma unroll
    for (int t = 0; t < 8; ++t) {
      f16x8 n0, n1, n2, n3;
      if (t < 7) {
        const f16* nvb = vb + (t + 1) * 2048;
        n0 = *(const f16x8*)(nvb);
        n1 = *(const f16x8*)(nvb + 512);
        n2 = *(const f16x8*)(nvb + 1024);
        n3 = *(const f16x8*)(nvb + 1536);
      }
      // stage half (t==0: s=0..7, t==4: s=8..15) into pstage; wave-private, DS in-order
      if (t == 0 || t == 4) {
        int hb = (t >> 2) * 8;
#pragma unroll
        for (int s2 = 0; s2 < 8; ++s2)
          *(f16x4*)(pst + r15 * 264 + s2 * 32 + g * 8) = p16[hb + s2];
        asm volatile("s_waitcnt lgkmcnt(0)" ::: "memory");
      }
      // 2 contiguous 512B row-store instrs (4 rows of this half per iter), PLAIN
      {
        int hh2 = t >> 2, rbase = (t & 3) * 4;
#pragma unroll
        for (int u = 0; u < 2; ++u) {
          int row = rbase + 2 * u + hi5;
          f16x4 pv4 = *(const f16x4*)(pst + row * 264 + c5 * 8);
          float rzr = rz[row];
          f32x4 wv;
#pragma unroll
          for (int r = 0; r < 4; ++r) wv[r] = (float)pv4[r] * rzr;
          *(f32x4*)(wrowbase + (size_t)row * 2048 + hh2 * 128 + 4 * c5) = wv;
        }
      }
      f16x8 af = __builtin_shufflevector(p16[2 * t], p16[2 * t + 1], 0, 1, 2, 3, 4, 5, 6, 7);
      acc[0] = MFMAH(af, v0, acc[0]);
      acc[1] = MFMAH(af, v1, acc[1]);
      acc[2] = MFMAH(af, v2, acc[2]);
      acc[3] = MFMAH(af, v3, acc[3]);
      v0 = n0; v1 = n1; v2 = n2; v3 = n3;
    }
#pragma unroll
    for (int dt = 0; dt < 4; ++dt)
#pragma unroll
      for (int r = 0; r < 4; ++r)
        pvh[wid][4 * g + r][dt * 16 + r15] = (f16)acc[dt][r];
  }
  __syncthreads();

  // ---- phase 3: cross-wave PV reduce (f16 partials) -> Abuf (f16 [B,T,C]) ----
  {
    int q = tid >> 5, d = (tid & 31) * 2;
    float a0 = 0.f, a1 = 0.f;
#pragma unroll
    for (int w8 = 0; w8 < 8; ++w8) {
      f16x2 v = *(const f16x2*)&pvh[w8][q][d];
      a0 += (float)v[0];
      a1 += (float)v[1];
    }
    float rzq = rz[q];
    f16x2 o2 = {(f16)(a0 * rzq), (f16)(a1 * rzq)};
    *(f16x2*)(Abuf + ((size_t)b * 2048 + q0 + q) * 1024 + h * 64 + d) = o2;
  }
}

extern "C" void kernel_launch(void* const* d_in, const int* in_sizes, int n_in,
                              void* d_out, int out_size, void* d_ws, size_t ws_size,
                              hipStream_t stream) {
  const float* query = (const float*)d_in[0];
  const float* key_i = (const float*)d_in[1];
  const float* value = (const float*)d_in[2];
  const float* q_w = (const float*)d_in[3];
  const float* q_b = (const float*)d_in[4];
  const float* k_w = (const float*)d_in[5];
  const float* k_b = (const float*)d_in[6];
  const float* v_w = (const float*)d_in[7];
  const float* v_b = (const float*)d_in[8];
  const float* o_w = (const float*)d_in[9];
  const float* o_b = (const float*)d_in[10];
  const int* mask = (const int*)d_in[11];
  float* out = (float*)d_out;
  float* wout = out + 4194304;  // weights output region

  // layout: [xf 33.6MB][Qf 8.4MB][Kf 8.4MB][VT2 8.4MB][Abuf 8.4MB] = 67 MB
  const size_t XFB = 16777216ull * 2;
  const size_t QB = 4194304ull * 2;
  if (ws_size < XFB + 4 * QB) return;
  f16* xf   = (f16*)d_ws;
  f16* Qf   = (f16*)((char*)d_ws + XFB);
  f16* Kf   = (f16*)((char*)d_ws + XFB + QB);
  f16* VT2  = (f16*)((char*)d_ws + XFB + 2 * QB);
  f16* Abuf = (f16*)((char*)d_ws + XFB + 3 * QB);

  conv_f16<<<16384, 256, 0, stream>>>(query, key_i, value, q_w, k_w, v_w, o_w, xf);
  gemm_qkv<<<dim3(8, 32, 3), 256, 0, stream>>>(xf, q_b, k_b, v_b, Qf, Kf, VT2);
  attn_kernel<<<4096, 512, 0, stream>>>(Qf, Kf, VT2, mask, wout, Abuf);
  gemm_o<<<dim3(8, 32), 256, 0, stream>>>(xf, Abuf, o_b, out);
}

// Round 13
// 247.193 us; speedup vs baseline: 1.2719x; 1.2719x over previous
//
#include <hip/hip_runtime.h>
#include <math.h>

// WheelMultiheadAttention on MI355X (gfx950) — v14: v12 attn (NT + XCD swizzle, best 253.5us)
// + BK=64 projection GEMMs (half the barriers, 32 MFMAs per barrier pair).
// B=2 T=2048 C=1024 H=16 D=64. Outputs: out [2,2048,1024] f32, weights [2,16,2048,2048] f32.

typedef _Float16 f16;
typedef _Float16 f16x2 __attribute__((ext_vector_type(2)));
typedef _Float16 f16x4 __attribute__((ext_vector_type(4)));
typedef _Float16 f16x8 __attribute__((ext_vector_type(8)));
typedef float  f32x2  __attribute__((ext_vector_type(2)));
typedef float  f32x4  __attribute__((ext_vector_type(4)));

#define MFMAH(a, b, c)  __builtin_amdgcn_mfma_f32_16x16x32_f16((a), (b), (c), 0, 0, 0)

__device__ __forceinline__ void gload16(void* lds, const void* g) {
  __builtin_amdgcn_global_load_lds((__attribute__((address_space(1))) void*)(g),
                                   (__attribute__((address_space(3))) void*)(lds),
                                   16, 0, 0);
}

// ---------------- fused f32 -> f16 convert (query|key|value|q_w|k_w|v_w|o_w) ----------------
__global__ __launch_bounds__(256) void conv_f16(const float* __restrict__ q, const float* __restrict__ k,
                                                const float* __restrict__ v, const float* __restrict__ qw,
                                                const float* __restrict__ kw, const float* __restrict__ vw,
                                                const float* __restrict__ ow, f16* __restrict__ xf) {
  long long i = ((long long)blockIdx.x * 256 + threadIdx.x) * 4;
  const float* src;
  long long off;
  if (i < 4194304)       { src = q;  off = 0; }
  else if (i < 8388608)  { src = k;  off = 4194304; }
  else if (i < 12582912) { src = v;  off = 8388608; }
  else if (i < 13631488) { src = qw; off = 12582912; }
  else if (i < 14680064) { src = kw; off = 13631488; }
  else if (i < 15728640) { src = vw; off = 14680064; }
  else                   { src = ow; off = 15728640; }
  f32x4 val = *(const f32x4*)(src + (i - off));
  f16x4 h;
#pragma unroll
  for (int r = 0; r < 4; ++r) h[r] = (f16)val[r];
  *(f16x4*)(xf + i) = h;
}

// ---------------- GEMM helpers: 128x128 tile, K-step 64, stride-1024 sources ----------------
// LDS tile [128 rows][64 cols] f16 = 16 KB; row = 8 x 16B chunks, XOR-swizzled by row&7.
__device__ __forceinline__ void stage64(f16* lds, const f16* g, int row0, int kc, int tid) {
#pragma unroll
  for (int j = 0; j < 4; ++j) {
    int chunk = j * 256 + tid;
    int r = chunk >> 3, cpos = chunk & 7;
    int csrc = cpos ^ (r & 7);
    gload16((char*)lds + chunk * 16,
            (const char*)(g + (size_t)(row0 + r) * 1024 + kc) + csrc * 16);
  }
}

__device__ __forceinline__ f16x8 frag64(const f16* lds, int row, int c) {
  int pos = c ^ (row & 7);
  return *(const f16x8*)((const char*)lds + row * 128 + pos * 16);
}

// K-loop core: acc[fm][fn] += A[o0+..][:] . X[t0+..][:] over K=1024, BK=64
__device__ __forceinline__ void gemm_core(const f16* A, const f16* X, int o0, int t0, int tid,
                                          f16* sA, f16* sB, f32x4 acc[4][4]) {
  int wid = tid >> 6, lane = tid & 63;
  int wm = wid >> 1, wn = wid & 1, g = lane >> 4, r15 = lane & 15;
  for (int kc = 0; kc < 1024; kc += 64) {
    __syncthreads();
    stage64(sA, A, o0, kc, tid);
    stage64(sB, X, t0, kc, tid);
    __syncthreads();
    f16x8 a0[4], a1[4], x0[4], x1[4];
#pragma unroll
    for (int f = 0; f < 4; ++f) {
      int ra = wm * 64 + f * 16 + r15;
      int rx = wn * 64 + f * 16 + r15;
      a0[f] = frag64(sA, ra, g);
      a1[f] = frag64(sA, ra, 4 + g);
      x0[f] = frag64(sB, rx, g);
      x1[f] = frag64(sB, rx, 4 + g);
    }
#pragma unroll
    for (int fm = 0; fm < 4; ++fm)
#pragma unroll
      for (int fn = 0; fn < 4; ++fn) {
        acc[fm][fn] = MFMAH(a0[fm], x0[fn], acc[fm][fn]);
        acc[fm][fn] = MFMAH(a1[fm], x1[fn], acc[fm][fn]);
      }
  }
}

// ---------------- fused Q/K/V projections (blockIdx.z = 0:Q, 1:K, 2:V) ----------------
__global__ __launch_bounds__(256, 3) void gemm_qkv(const f16* __restrict__ xf,
                                                   const float* __restrict__ q_b, const float* __restrict__ k_b,
                                                   const float* __restrict__ v_b,
                                                   f16* __restrict__ Qf, f16* __restrict__ Kf,
                                                   f16* __restrict__ VT2) {
  __shared__ f16 sA[8192], sB[8192];
  int z = blockIdx.z;
  int tid = threadIdx.x;
  int wid = tid >> 6, lane = tid & 63;
  int wm = wid >> 1, wn = wid & 1, g = lane >> 4, r15 = lane & 15;
  f32x4 acc[4][4] = {};
  if (z == 2) {
    const f16* X = xf + 8388608;   // value
    const f16* W = xf + 14680064;  // v_w
    int o0 = blockIdx.x * 128, t0 = blockIdx.y * 128;
    gemm_core(X, W, t0, o0, tid, sA, sB, acc);
#pragma unroll
    for (int fm = 0; fm < 4; ++fm)
#pragma unroll
      for (int fn = 0; fn < 4; ++fn) {
        int tb = t0 + wm * 64 + fm * 16 + 4 * g;
        int o  = o0 + wn * 64 + fn * 16 + r15;
        int bb = tb >> 11, tl = tb & 2047, hh = o >> 6, dd = o & 63;
        int ch = tl >> 5, c = tl & 31;
        int slotbase = (c < 16) ? ((c >> 2) << 3) : ((((c - 16) >> 2) << 3) + 4);
        float bo = v_b[o];
        f16x4 v4;
#pragma unroll
        for (int r = 0; r < 4; ++r) v4[r] = (f16)(acc[fm][fn][r] + bo);
        *(f16x4*)(VT2 + ((((size_t)bb * 16 + hh) * 64 + ch) * 64 + dd) * 32 + slotbase) = v4;
      }
  } else {
    const f16* A = xf + (z ? 13631488 : 12582912);
    const f16* X = xf + (z ? 4194304 : 0);
    const float* bias = z ? k_b : q_b;
    f16* Yf = z ? Kf : Qf;
    float scale = z ? 1.0f : 0.125f;
    int o0 = blockIdx.x * 128, t0 = blockIdx.y * 128;
    gemm_core(A, X, o0, t0, tid, sA, sB, acc);
#pragma unroll
    for (int fm = 0; fm < 4; ++fm)
#pragma unroll
      for (int fn = 0; fn < 4; ++fn) {
        int ob = o0 + wm * 64 + fm * 16 + 4 * g;
        int t  = t0 + wn * 64 + fn * 16 + r15;
        int bb = t >> 11, tl = t & 2047, hh = ob >> 6, dd = ob & 63;
        size_t base = (((size_t)bb * 16 + hh) * 2048 + tl) * 64 + dd;
        f16x4 vh;
#pragma unroll
        for (int r = 0; r < 4; ++r)
          vh[r] = (f16)((acc[fm][fn][r] + bias[ob + r]) * scale);
        *(f16x4*)(Yf + base) = vh;
      }
  }
}

// ---------------- O projection: Out[t][o] = A[t][:].o_w[o][:] + b, f32 ----------------
__global__ __launch_bounds__(256, 3) void gemm_o(const f16* __restrict__ xf, const f16* __restrict__ Abuf,
                                                 const float* __restrict__ o_b, float* __restrict__ OutF) {
  __shared__ f16 sA[8192], sB[8192];
  const f16* A = xf + 15728640;  // o_w
  int tid = threadIdx.x;
  int o0 = blockIdx.x * 128, t0 = blockIdx.y * 128;
  int wid = tid >> 6, lane = tid & 63;
  int wm = wid >> 1, wn = wid & 1, g = lane >> 4, r15 = lane & 15;
  f32x4 acc[4][4] = {};
  gemm_core(A, Abuf, o0, t0, tid, sA, sB, acc);
#pragma unroll
  for (int fm = 0; fm < 4; ++fm)
#pragma unroll
    for (int fn = 0; fn < 4; ++fn) {
      int ob = o0 + wm * 64 + fm * 16 + 4 * g;
      int t  = t0 + wn * 64 + fn * 16 + r15;
      f32x4 v;
#pragma unroll
      for (int r = 0; r < 4; ++r) v[r] = acc[fm][fn][r] + o_b[ob + r];
      *(f32x4*)(OutF + (size_t)t * 1024 + ob) = v;
    }
}

// ---------------- fused attention (identical to v12: NT stores + XCD swizzle) ----------------
__global__ __launch_bounds__(512, 6) void attn_kernel(
    const f16* __restrict__ Qf, const f16* __restrict__ Kf,
    const f16* __restrict__ VT2, const int* __restrict__ mask,
    float* __restrict__ wout, f16* __restrict__ Abuf) {
  __shared__ char smemA[8][4224];  // per-wave: phase1 K dbuf (2x2048B) -> phase2 pstage
  __shared__ f16 pvh[8][16][72];   // PV partials f16
  __shared__ float ps[128];        // row-sum partials [q][wave]
  __shared__ float rz[16];
  int tid = threadIdx.x;
  int wid = tid >> 6, lane = tid & 63;
  int g = lane >> 4, r15 = lane & 15;
  // XCD-aware bijective swizzle: each XCD gets a contiguous 512-block slice (4 bh).
  int bid = blockIdx.x;
  int swz = (bid & 7) * 512 + (bid >> 3);
  int qt = swz & 127, bh = swz >> 7;
  int b = bh >> 4, h = bh & 15;
  int q0 = qt * 16;

  // Q fragments (B-operand: col = q = lane&15). 1/8 scale folded into Qf.
  const f16* qp = Qf + ((size_t)bh * 2048 + q0 + r15) * 64 + 8 * g;
  f16x8 qh0 = *(const f16x8*)(qp);
  f16x8 qh1 = *(const f16x8*)(qp + 32);

  // pack this lane's 64 mask bits (k = wid*256 + s*16 + 4g + r) -> bit 4s+r
  const int* mp = mask + b * 2048 + wid * 256 + 4 * g;
  unsigned long long mb = 0;
#pragma unroll
  for (int t = 0; t < 16; ++t) {
    int4 ma = *(const int4*)(mp + t * 16);
    mb |= ((ma.x ? 1ull : 0ull) << (4 * t)) | ((ma.y ? 1ull : 0ull) << (4 * t + 1)) |
          ((ma.z ? 1ull : 0ull) << (4 * t + 2)) | ((ma.w ? 1ull : 0ull) << (4 * t + 3));
  }

  // ---- phase 1: swapped QK^T, async-LDS K staging, ds_reads pipelined 1 tile ahead ----
  f16* kb0 = (f16*)&smemA[wid][0];
  f16* kb1 = (f16*)&smemA[wid][2048];
  const f16* ksrcA = Kf + ((size_t)bh * 2048 + wid * 256 + (lane >> 3)) * 64 +
                     (((lane & 7) ^ ((lane >> 3) & 7)) * 8);
  const f16* ksrcB = ksrcA + 8 * 64;

  gload16(kb0, ksrcA);
  gload16(kb0 + 512, ksrcB);
  gload16(kb1, ksrcA + 1024);
  gload16(kb1 + 512, ksrcB + 1024);
  asm volatile("s_waitcnt vmcnt(2)" ::: "memory");  // tile 0 staged
  int key = r15 & 7;
  f16x8 c0 = *(const f16x8*)(kb0 + r15 * 64 + ((g ^ key) * 8));
  f16x8 c1 = *(const f16x8*)(kb0 + r15 * 64 + (((g + 4) ^ key) * 8));

  float psum = 0.f;
  f16x4 p16[16];
#pragma unroll
  for (int s = 0; s < 16; ++s) {
    if (s < 14) {
      asm volatile("s_waitcnt lgkmcnt(0)" ::: "memory");  // tile-s frag reads done
      f16* nb = (s & 1) ? kb1 : kb0;
      gload16(nb, ksrcA + (s + 2) * 1024);
      gload16(nb + 512, ksrcB + (s + 2) * 1024);
    }
    f16x8 n0, n1;
    if (s < 15) {
      if (s < 14) asm volatile("s_waitcnt vmcnt(2)" ::: "memory");
      else        asm volatile("s_waitcnt vmcnt(0)" ::: "memory");
      const f16* nt = ((s + 1) & 1) ? kb1 : kb0;
      n0 = *(const f16x8*)(nt + r15 * 64 + ((g ^ key) * 8));
      n1 = *(const f16x8*)(nt + r15 * 64 + (((g + 4) ^ key) * 8));
    }
    f32x4 sc = {0.f, 0.f, 0.f, 0.f};
    sc = MFMAH(c0, qh0, sc);   // A = K rows (k), B = Q (cols q)
    sc = MFMAH(c1, qh1, sc);
    f16x4 pk;
#pragma unroll
    for (int r = 0; r < 4; ++r) {
      float e = ((mb >> (4 * s + r)) & 1) ? 0.f : __expf(sc[r]);
      psum += e;
      pk[r] = (f16)e;
    }
    p16[s] = pk;
    c0 = n0;
    c1 = n1;
  }

  // in-wave row-sum reduce across g (lanes sharing q=r15)
  psum += __shfl_xor(psum, 16);
  psum += __shfl_xor(psum, 32);
  if (lane < 16) ps[lane * 8 + wid] = psum;
  __syncthreads();

  // finalize row sums -> rz (wheel: z==0 -> 0)
  if (tid < 128) {
    float z = ps[tid];
#pragma unroll
    for (int m = 1; m <= 4; m <<= 1) z += __shfl_xor(z, m);
    if ((tid & 7) == 0) rz[tid >> 3] = (z > 0.f) ? 1.0f / z : 0.0f;
  }
  __syncthreads();

  // ---- phase 2: PV + transpose-staged contiguous NT weight stores ----
  f32x4 acc[4] = {};
  {
    char* pst = &smemA[wid][0];
    int c5 = lane & 31, hi5 = lane >> 5;
    float* wrowbase = wout + ((size_t)bh * 2048 + q0) * 2048 + wid * 256;
    const f16* vb = VT2 + (((size_t)bh * 64 + wid * 8) * 64 + r15) * 32 + g * 8;
    f16x8 v0 = *(const f16x8*)(vb);
    f16x8 v1 = *(const f16x8*)(vb + 512);
    f16x8 v2 = *(const f16x8*)(vb + 1024);
    f16x8 v3 = *(const f16x8*)(vb + 1536);
#pragma unroll
    for (int t = 0; t < 8; ++t) {
      f16x8 n0, n1, n2, n3;
      if (t < 7) {
        const f16* nvb = vb + (t + 1) * 2048;
        n0 = *(const f16x8*)(nvb);
        n1 = *(const f16x8*)(nvb + 512);
        n2 = *(const f16x8*)(nvb + 1024);
        n3 = *(const f16x8*)(nvb + 1536);
      }
      // stage half (t==0: s=0..7, t==4: s=8..15) into pstage; wave-private, DS in-order
      if (t == 0 || t == 4) {
        int hb = (t >> 2) * 8;
#pragma unroll
        for (int s2 = 0; s2 < 8; ++s2)
          *(f16x4*)(pst + r15 * 264 + s2 * 32 + g * 8) = p16[hb + s2];
        asm volatile("s_waitcnt lgkmcnt(0)" ::: "memory");
      }
      // 2 contiguous 512B row-store instrs (4 rows of this half per iter), NT
      {
        int hh2 = t >> 2, rbase = (t & 3) * 4;
#pragma unroll
        for (int u = 0; u < 2; ++u) {
          int row = rbase + 2 * u + hi5;
          f16x4 pv4 = *(const f16x4*)(pst + row * 264 + c5 * 8);
          float rzr = rz[row];
          f32x4 wv;
#pragma unroll
          for (int r = 0; r < 4; ++r) wv[r] = (float)pv4[r] * rzr;
          __builtin_nontemporal_store(wv,
              (f32x4*)(wrowbase + (size_t)row * 2048 + hh2 * 128 + 4 * c5));
        }
      }
      f16x8 af = __builtin_shufflevector(p16[2 * t], p16[2 * t + 1], 0, 1, 2, 3, 4, 5, 6, 7);
      acc[0] = MFMAH(af, v0, acc[0]);
      acc[1] = MFMAH(af, v1, acc[1]);
      acc[2] = MFMAH(af, v2, acc[2]);
      acc[3] = MFMAH(af, v3, acc[3]);
      v0 = n0; v1 = n1; v2 = n2; v3 = n3;
    }
#pragma unroll
    for (int dt = 0; dt < 4; ++dt)
#pragma unroll
      for (int r = 0; r < 4; ++r)
        pvh[wid][4 * g + r][dt * 16 + r15] = (f16)acc[dt][r];
  }
  __syncthreads();

  // ---- phase 3: cross-wave PV reduce (f16 partials) -> Abuf (f16 [B,T,C]) ----
  {
    int q = tid >> 5, d = (tid & 31) * 2;
    float a0 = 0.f, a1 = 0.f;
#pragma unroll
    for (int w8 = 0; w8 < 8; ++w8) {
      f16x2 v = *(const f16x2*)&pvh[w8][q][d];
      a0 += (float)v[0];
      a1 += (float)v[1];
    }
    float rzq = rz[q];
    f16x2 o2 = {(f16)(a0 * rzq), (f16)(a1 * rzq)};
    *(f16x2*)(Abuf + ((size_t)b * 2048 + q0 + q) * 1024 + h * 64 + d) = o2;
  }
}

extern "C" void kernel_launch(void* const* d_in, const int* in_sizes, int n_in,
                              void* d_out, int out_size, void* d_ws, size_t ws_size,
                              hipStream_t stream) {
  const float* query = (const float*)d_in[0];
  const float* key_i = (const float*)d_in[1];
  const float* value = (const float*)d_in[2];
  const float* q_w = (const float*)d_in[3];
  const float* q_b = (const float*)d_in[4];
  const float* k_w = (const float*)d_in[5];
  const float* k_b = (const float*)d_in[6];
  const float* v_w = (const float*)d_in[7];
  const float* v_b = (const float*)d_in[8];
  const float* o_w = (const float*)d_in[9];
  const float* o_b = (const float*)d_in[10];
  const int* mask = (const int*)d_in[11];
  float* out = (float*)d_out;
  float* wout = out + 4194304;  // weights output region

  // layout: [xf 33.6MB][Qf 8.4MB][Kf 8.4MB][VT2 8.4MB][Abuf 8.4MB] = 67 MB
  const size_t XFB = 16777216ull * 2;
  const size_t QB = 4194304ull * 2;
  if (ws_size < XFB + 4 * QB) return;
  f16* xf   = (f16*)d_ws;
  f16* Qf   = (f16*)((char*)d_ws + XFB);
  f16* Kf   = (f16*)((char*)d_ws + XFB + QB);
  f16* VT2  = (f16*)((char*)d_ws + XFB + 2 * QB);
  f16* Abuf = (f16*)((char*)d_ws + XFB + 3 * QB);

  conv_f16<<<16384, 256, 0, stream>>>(query, key_i, value, q_w, k_w, v_w, o_w, xf);
  gemm_qkv<<<dim3(8, 32, 3), 256, 0, stream>>>(xf, q_b, k_b, v_b, Qf, Kf, VT2);
  attn_kernel<<<4096, 512, 0, stream>>>(Qf, Kf, VT2, mask, wout, Abuf);
  gemm_o<<<dim3(8, 32), 256, 0, stream>>>(xf, Abuf, o_b, out);
}